// Round 7
// baseline (186.798 us; speedup 1.0000x reference)
//
#include <hip/hip_runtime.h>
#include <math.h>

#define BB 32
#define SS 512
#define HH 768
#define FDD 64
#define PP 30
#define NR 16384   // BB*SS rows

typedef __attribute__((ext_vector_type(8))) short short8v;
typedef __attribute__((ext_vector_type(4))) float f32x4;

// ws float offsets
#define O_TEXTF  0u        // fp32 text TRANSPOSED [32][16384]
#define O_AUDF   524288u   // fp32 audio TRANSPOSED [32][16384]
#define O_ATT    1048576u  // 32*512 att weights
#define O_FPART  1081344u  // 8*32*768 pv partials
#define O_WDT    1572864u  // 768*768 transposed W_dense
#define O_WTB    2162688u  // 24576 ushort (bf16 Wt frag-ordered)
#define O_WAB    2174976u  // 2048 ushort  (bf16 Wa frag-ordered)
#define O_TEXTB  2176000u  // bf16 text  [16384][32]
#define O_AUDB   2438144u  // bf16 audio [16384][32]
#define O_SUMSQ  2700288u  // 1

__device__ __forceinline__ unsigned short f2bf(float f){
  unsigned u = __float_as_uint(f);
  unsigned r = (u + 0x7fffu + ((u>>16)&1u)) >> 16;   // RNE
  return (unsigned short)r;
}
__device__ __forceinline__ short8v pack8(const float4& p0, const float4& p1){
  union { short8v v; unsigned u[4]; } r;
  r.u[0] = f2bf(p0.x) | ((unsigned)f2bf(p0.y) << 16);
  r.u[1] = f2bf(p0.z) | ((unsigned)f2bf(p0.w) << 16);
  r.u[2] = f2bf(p1.x) | ((unsigned)f2bf(p1.y) << 16);
  r.u[3] = f2bf(p1.z) | ((unsigned)f2bf(p1.w) << 16);
  return r.v;
}

// ---- prep: LDS-tiled WdT transpose (0..575), bf16 frag Wt/Wa (576..679), sumsq zero (680) ----
__global__ __launch_bounds__(256) void k_prep(const float* __restrict__ Wd,
    const float* __restrict__ Wt, const float* __restrict__ Wa, float* __restrict__ ws){
  const int bi = blockIdx.x, tid = threadIdx.x;
  if (bi < 576){
    __shared__ float L[32][33];
    const int tx = bi % 24, ty = bi / 24;
    const int lx = tid & 31, ly = tid >> 5;
    #pragma unroll
    for (int i = 0; i < 4; ++i)
      L[ly + i*8][lx] = Wd[(size_t)(ty*32 + ly + i*8)*HH + tx*32 + lx];
    __syncthreads();
    #pragma unroll
    for (int i = 0; i < 4; ++i)
      ws[O_WDT + (size_t)(tx*32 + ly + i*8)*HH + ty*32 + lx] = L[lx][ly + i*8];
  } else if (bi < 680){
    int idx = (bi - 576)*256 + tid;
    if (idx < 24576){
      int j = idx & 7, lane = (idx>>3) & 63, t = idx>>9;   // t = n*24+ks
      int n = t / 24, ks = t - n*24;
      int p = n*16 + (lane & 15);
      int k = ks*32 + ((lane>>4)<<3) + j;
      float v = (p < PP) ? Wt[p*HH + k] : 0.0f;
      ((unsigned short*)(ws + O_WTB))[idx] = f2bf(v);
    } else {
      int fa = idx - 24576;   // < 2048
      int j = fa & 7, lane = (fa>>3) & 63, t = fa>>9;      // t = n*2+ks
      int n = t>>1, ks = t & 1;
      int p = n*16 + (lane & 15);
      int k = ks*32 + ((lane>>4)<<3) + j;
      float v = (p < PP) ? Wa[p*FDD + k] : 0.0f;
      ((unsigned short*)(ws + O_WAB))[fa] = f2bf(v);
    }
  } else if (tid == 0){
    ws[O_SUMSQ] = 0.0f;
  }
}

// ---- projection via bf16 MFMA, NO LDS / NO BARRIERS: A-frag loaded direct from global ----
// wave w handles rows rowbase + w*16 .. +16; lane: row = w*16+(l&15), k-off = (l>>4)*8
__global__ __launch_bounds__(256) void k_proj(const float* __restrict__ hs,
    const float* __restrict__ ad, float* __restrict__ ws){
  const int tid = threadIdx.x;
  const int lane = tid & 63, w = tid >> 6;
  const int rowbase = blockIdx.x * 64;
  const int mrow = rowbase + w*16 + (lane & 15);
  const int koff = (lane >> 4) << 3;
  const short8v* WTB = (const short8v*)(ws + O_WTB);
  const short8v* WAB = (const short8v*)(ws + O_WAB);
  f32x4 accT0 = {0,0,0,0}, accT1 = {0,0,0,0};

  const float* hp = hs + (size_t)mrow*HH + koff;
  #pragma unroll 4
  for (int ks = 0; ks < 24; ++ks){
    float4 p0 = *(const float4*)(hp + ks*32);
    float4 p1 = *(const float4*)(hp + ks*32 + 4);
    short8v a = pack8(p0, p1);
    accT0 = __builtin_amdgcn_mfma_f32_16x16x32_bf16(a, WTB[ks*64 + lane], accT0, 0, 0, 0);
    accT1 = __builtin_amdgcn_mfma_f32_16x16x32_bf16(a, WTB[(24 + ks)*64 + lane], accT1, 0, 0, 0);
  }

  f32x4 accA0 = {0,0,0,0}, accA1 = {0,0,0,0};
  const float* ap = ad + (size_t)mrow*FDD + koff;
  #pragma unroll
  for (int ks = 0; ks < 2; ++ks){
    float4 q0 = *(const float4*)(ap + ks*32);
    float4 q1 = *(const float4*)(ap + ks*32 + 4);
    short8v a = pack8(q0, q1);
    accA0 = __builtin_amdgcn_mfma_f32_16x16x32_bf16(a, WAB[ks*64 + lane], accA0, 0, 0, 0);
    accA1 = __builtin_amdgcn_mfma_f32_16x16x32_bf16(a, WAB[(2 + ks)*64 + lane], accA1, 0, 0, 0);
  }

  // epilogue: C layout col(p)=lane&15, row=(lane>>4)*4+r
  float* TF = ws + O_TEXTF;   // [32][16384]
  float* AF = ws + O_AUDF;
  unsigned short* TEXTB = (unsigned short*)(ws + O_TEXTB);  // [16384][32]
  unsigned short* AUDB  = (unsigned short*)(ws + O_AUDB);
  const int q4 = lane >> 4, pl = lane & 15;
  const int row0 = rowbase + w*16 + q4*4;
  float sq = 0.0f;
  #pragma unroll
  for (int r = 0; r < 4; ++r) sq += accT0[r]*accT0[r] + accT1[r]*accT1[r];
  // fp32 transposed: per-lane 4 consecutive rows for fixed p -> float4
  *(float4*)(TF + (size_t)pl*NR + row0)      = *(float4*)&accT0;
  *(float4*)(TF + (size_t)(pl+16)*NR + row0) = *(float4*)&accT1;
  *(float4*)(AF + (size_t)pl*NR + row0)      = *(float4*)&accA0;
  *(float4*)(AF + (size_t)(pl+16)*NR + row0) = *(float4*)&accA1;
  // bf16 row-major for gram fragments
  #pragma unroll
  for (int r = 0; r < 4; ++r){
    int row = row0 + r;
    TEXTB[(size_t)row*32 + pl]      = f2bf(accT0[r]);
    TEXTB[(size_t)row*32 + 16 + pl] = f2bf(accT1[r]);
    AUDB[(size_t)row*32 + pl]       = f2bf(accA0[r]);
    AUDB[(size_t)row*32 + 16 + pl]  = f2bf(accA1[r]);
  }
  #pragma unroll
  for (int off = 32; off; off >>= 1) sq += __shfl_xor(sq, off);
  if (lane == 0) atomicAdd(ws + O_SUMSQ, sq);
}

// ---- gram via bf16 MFMA, swapped operands -> float4 stores along t ----
__global__ __launch_bounds__(256) void k_gram(const float* __restrict__ ws,
    const float* __restrict__ twp, const float* __restrict__ awp, const float* __restrict__ fbp,
    float* __restrict__ out_text, float* __restrict__ out_fus){
  const int tid = threadIdx.x, lane = tid & 63, w = tid >> 6;
  const int tt = blockIdx.x, st = blockIdx.y, b = blockIdx.z;
  const unsigned short* TEXTB = (const unsigned short*)(ws + O_TEXTB);
  const unsigned short* AUDB  = (const unsigned short*)(ws + O_AUDB);
  const int q4 = lane >> 4, pl = lane & 15;
  const size_t srow  = (size_t)b*SS + st*64 + w*16 + pl;   // s-row for this lane
  const size_t trow0 = (size_t)b*SS + tt*64 + pl;          // t-row base
  short8v at = *(const short8v*)&TEXTB[srow*32 + q4*8];    // B-operand (s)
  short8v aa = *(const short8v*)&AUDB [srow*32 + q4*8];
  f32x4 z = {0,0,0,0};
  f32x4 ct[4], ca[4];
  #pragma unroll
  for (int n = 0; n < 4; ++n){
    short8v bt = *(const short8v*)&TEXTB[(trow0 + n*16)*32 + q4*8];  // A-operand (t)
    short8v ba = *(const short8v*)&AUDB [(trow0 + n*16)*32 + q4*8];
    ct[n] = __builtin_amdgcn_mfma_f32_16x16x32_bf16(bt, at, z, 0, 0, 0);  // D[t][s]
    ca[n] = __builtin_amdgcn_mfma_f32_16x16x32_bf16(ba, aa, z, 0, 0, 0);
  }
  const float inv_s = 1.0f / sqrtf(ws[O_SUMSQ]);
  const float tw = twp[0], aw = awp[0], fb = fbp[0];
  const int s = st*64 + w*16 + pl;          // output row (col of D)
  const int tbase = tt*64;                  // D rows are t
  #pragma unroll
  for (int n = 0; n < 4; ++n){
    float4 vt, vf;
    float* pt_ = (float*)&vt; float* pf_ = (float*)&vf;
    #pragma unroll
    for (int r = 0; r < 4; ++r){
      float t_ = fmaxf(ct[n][r]*inv_s, 0.0f);
      float a_ = fmaxf(ca[n][r], 0.0f);
      pt_[r] = t_;
      pf_[r] = fmaxf(tw*t_ + aw*a_ + fb, 0.0f);
    }
    size_t o = ((size_t)b*SS + s)*SS + tbase + n*16 + q4*4;
    *(float4*)(out_text + o) = vt;
    *(float4*)(out_fus  + o) = vf;
  }
}

// ---- row-0 scores + softmax fused: one block of 512 per batch ----
__global__ __launch_bounds__(512) void k_att(float* __restrict__ ws, const float* __restrict__ amask,
    const float* __restrict__ twp, const float* __restrict__ awp, const float* __restrict__ fbp){
  const int b = blockIdx.x, tid = threadIdx.x;
  __shared__ float t0[32], a0[32];
  __shared__ float red[512];
  const float* TF = ws + O_TEXTF;
  const float* AF = ws + O_AUDF;
  if (tid < 32) t0[tid] = TF[(size_t)tid*NR + (size_t)b*SS];
  else if (tid < 64) a0[tid-32] = AF[(size_t)(tid-32)*NR + (size_t)b*SS];
  __syncthreads();
  const float inv_s = 1.0f / sqrtf(ws[O_SUMSQ]);
  const float tw = twp[0], aw = awp[0], fb = fbp[0];
  const float m0 = amask[(size_t)b*SS];
  const size_t base = (size_t)b*SS + tid;
  float dt = 0.f, da = 0.f;
  #pragma unroll
  for (int p = 0; p < 32; ++p){
    dt += t0[p]*TF[(size_t)p*NR + base];
    da += a0[p]*AF[(size_t)p*NR + base];
  }
  const float sv = tw*fmaxf(dt*inv_s, 0.f) + aw*fmaxf(da, 0.f) + fb
                 + amask[base] + m0;
  red[tid] = sv;
  __syncthreads();
  for (int s2 = 256; s2 > 0; s2 >>= 1){ if (tid < s2) red[tid] = fmaxf(red[tid], red[tid+s2]); __syncthreads(); }
  const float m = red[0];
  __syncthreads();
  const float e = __expf(sv - m);
  red[tid] = e;
  __syncthreads();
  for (int s2 = 256; s2 > 0; s2 >>= 1){ if (tid < s2) red[tid] += red[tid+s2]; __syncthreads(); }
  ws[O_ATT + base] = e / red[0];
}

// ---- row-0 PV: (3 c-chunks, 8 t-chunks, 32 b) ----
__global__ __launch_bounds__(256) void k_pv(const float* __restrict__ hs, float* __restrict__ ws){
  const int tid = threadIdx.x;
  const int cx = blockIdx.x, th = blockIdx.y, b = blockIdx.z;
  __shared__ float a[64];
  if (tid < 64) a[tid] = ws[O_ATT + (size_t)b*SS + th*64 + tid];
  __syncthreads();
  const int c = cx*256 + tid;
  const float* hp = hs + ((size_t)b*SS + th*64)*HH + c;
  float acc = 0.f;
  #pragma unroll 8
  for (int t = 0; t < 64; ++t) acc += a[t]*hp[(size_t)t*HH];
  if (th == 0) acc += hs[(size_t)b*SS*HH + c];   // residual
  ws[O_FPART + ((size_t)th*BB + b)*HH + c] = acc;
}

// ---- dense + LN fused: 32 blocks x 1024 threads, split-c in-block ----
__global__ __launch_bounds__(1024) void k_dense_ln(const float* __restrict__ ws,
    const float* __restrict__ bd, const float* __restrict__ lw, const float* __restrict__ lb,
    float* __restrict__ out){
  const int b = blockIdx.x, tid = threadIdx.x;
  __shared__ float f[HH];
  __shared__ float part[4*HH];
  __shared__ float red[1024];
  if (tid < HH){
    float s = 0.f;
    #pragma unroll
    for (int th = 0; th < 8; ++th) s += ws[O_FPART + ((size_t)th*BB + b)*HH + tid];
    f[tid] = s;
  }
  __syncthreads();
  const int cc = tid >> 8, o = tid & 255;
  const float* Wp = ws + O_WDT + (size_t)(cc*192)*HH;
  const float* fp = f + cc*192;
  float a0 = 0.f, a1 = 0.f, a2 = 0.f;
  #pragma unroll 8
  for (int i = 0; i < 192; ++i){
    const float fv = fp[i];
    const float* wr = Wp + (size_t)i*HH + o;
    a0 += fv*wr[0];
    a1 += fv*wr[256];
    a2 += fv*wr[512];
  }
  part[cc*HH + o]       = a0;
  part[cc*HH + o + 256] = a1;
  part[cc*HH + o + 512] = a2;
  __syncthreads();
  float h = 0.f;
  if (tid < HH)
    h = part[tid] + part[HH + tid] + part[2*HH + tid] + part[3*HH + tid] + bd[tid];
  red[tid] = (tid < HH) ? h : 0.f;
  __syncthreads();
  for (int s2 = 512; s2 > 0; s2 >>= 1){ if (tid < s2) red[tid] += red[tid+s2]; __syncthreads(); }
  const float u = red[0]*(1.0f/HH);
  __syncthreads();
  const float d = h - u;
  red[tid] = (tid < HH) ? d*d : 0.f;
  __syncthreads();
  for (int s2 = 512; s2 > 0; s2 >>= 1){ if (tid < s2) red[tid] += red[tid+s2]; __syncthreads(); }
  const float isd = 1.0f / sqrtf(red[0]*(1.0f/HH) + 1e-12f);
  if (tid < HH)
    out[(size_t)b*HH + tid] = lw[tid]*d*isd + lb[tid];
}

extern "C" void kernel_launch(void* const* d_in, const int* in_sizes, int n_in,
                              void* d_out, int out_size, void* d_ws, size_t ws_size,
                              hipStream_t stream){
  const float* hs    = (const float*)d_in[0];
  const float* ad    = (const float*)d_in[1];
  const float* amask = (const float*)d_in[2];
  const float* Wt    = (const float*)d_in[3];
  const float* Wa    = (const float*)d_in[4];
  const float* twp   = (const float*)d_in[5];
  const float* awp   = (const float*)d_in[6];
  const float* fbp   = (const float*)d_in[7];
  const float* Wd    = (const float*)d_in[8];
  const float* bd    = (const float*)d_in[9];
  const float* lw    = (const float*)d_in[10];
  const float* lb    = (const float*)d_in[11];
  float* out = (float*)d_out;
  float* ws  = (float*)d_ws;
  float* out_h    = out;
  float* out_text = out + (size_t)BB*HH;
  float* out_fus  = out_text + (size_t)BB*SS*SS;

  hipLaunchKernelGGL(k_prep, dim3(681), dim3(256), 0, stream, Wd, Wt, Wa, ws);
  hipLaunchKernelGGL(k_proj, dim3(NR/64), dim3(256), 0, stream, hs, ad, ws);
  hipLaunchKernelGGL(k_gram, dim3(8,8,BB), dim3(256), 0, stream, ws, twp, awp, fbp, out_text, out_fus);
  hipLaunchKernelGGL(k_att, dim3(BB), dim3(512), 0, stream, ws, amask, twp, awp, fbp);
  hipLaunchKernelGGL(k_pv, dim3(3,8,BB), dim3(256), 0, stream, hs, ws);
  hipLaunchKernelGGL(k_dense_ln, dim3(BB), dim3(1024), 0, stream, ws, bd, lw, lb, out_h);
}

// Round 9
// 182.304 us; speedup vs baseline: 1.0247x; 1.0247x over previous
//
#include <hip/hip_runtime.h>
#include <math.h>

#define BB 32
#define SS 512
#define HH 768
#define FDD 64
#define PP 30
#define NR 16384   // BB*SS rows

typedef __attribute__((ext_vector_type(8))) short short8v;
typedef __attribute__((ext_vector_type(4))) float f32x4;

// ws float offsets
#define O_TEXTF  0u        // fp32 text TRANSPOSED [32][16384]
#define O_AUDF   524288u   // fp32 audio TRANSPOSED [32][16384]
#define O_ATT    1048576u  // 32*512 att weights
#define O_FPART  1081344u  // 8*32*768 pv partials
#define O_HPART  1277952u  // 12*32*768 dense partials
#define O_WDT    1572864u  // 768*768 transposed W_dense
#define O_WTB    2162688u  // 24576 ushort (bf16 Wt frag-ordered)
#define O_WAB    2174976u  // 2048 ushort  (bf16 Wa frag-ordered)
#define O_TEXTB  2176000u  // bf16 text  [16384][32]
#define O_AUDB   2438144u  // bf16 audio [16384][32]
#define O_SUMSQ  2700288u  // 1

__device__ __forceinline__ unsigned short f2bf(float f){
  unsigned u = __float_as_uint(f);
  unsigned r = (u + 0x7fffu + ((u>>16)&1u)) >> 16;   // RNE
  return (unsigned short)r;
}
__device__ __forceinline__ short8v pack8(const f32x4& p0, const f32x4& p1){
  union { short8v v; unsigned u[4]; } r;
  r.u[0] = f2bf(p0[0]) | ((unsigned)f2bf(p0[1]) << 16);
  r.u[1] = f2bf(p0[2]) | ((unsigned)f2bf(p0[3]) << 16);
  r.u[2] = f2bf(p1[0]) | ((unsigned)f2bf(p1[1]) << 16);
  r.u[3] = f2bf(p1[2]) | ((unsigned)f2bf(p1[3]) << 16);
  return r.v;
}

// ---- prep: LDS-tiled WdT transpose (0..575), bf16 frag Wt/Wa (576..679), sumsq zero (680) ----
__global__ __launch_bounds__(256) void k_prep(const float* __restrict__ Wd,
    const float* __restrict__ Wt, const float* __restrict__ Wa, float* __restrict__ ws){
  const int bi = blockIdx.x, tid = threadIdx.x;
  if (bi < 576){
    __shared__ float L[32][33];
    const int tx = bi % 24, ty = bi / 24;
    const int lx = tid & 31, ly = tid >> 5;
    #pragma unroll
    for (int i = 0; i < 4; ++i)
      L[ly + i*8][lx] = Wd[(size_t)(ty*32 + ly + i*8)*HH + tx*32 + lx];
    __syncthreads();
    #pragma unroll
    for (int i = 0; i < 4; ++i)
      ws[O_WDT + (size_t)(tx*32 + ly + i*8)*HH + ty*32 + lx] = L[lx][ly + i*8];
  } else if (bi < 680){
    int idx = (bi - 576)*256 + tid;
    if (idx < 24576){
      int j = idx & 7, lane = (idx>>3) & 63, t = idx>>9;   // t = n*24+ks
      int n = t / 24, ks = t - n*24;
      int p = n*16 + (lane & 15);
      int k = ks*32 + ((lane>>4)<<3) + j;
      float v = (p < PP) ? Wt[p*HH + k] : 0.0f;
      ((unsigned short*)(ws + O_WTB))[idx] = f2bf(v);
    } else {
      int fa = idx - 24576;   // < 2048
      int j = fa & 7, lane = (fa>>3) & 63, t = fa>>9;      // t = n*2+ks
      int n = t>>1, ks = t & 1;
      int p = n*16 + (lane & 15);
      int k = ks*32 + ((lane>>4)<<3) + j;
      float v = (p < PP) ? Wa[p*FDD + k] : 0.0f;
      ((unsigned short*)(ws + O_WAB))[fa] = f2bf(v);
    }
  } else if (tid == 0){
    ws[O_SUMSQ] = 0.0f;
  }
}

// ---- projection via bf16 MFMA, no LDS/barriers; NT loads on single-use hs/ad streams ----
__global__ __launch_bounds__(256) void k_proj(const float* __restrict__ hs,
    const float* __restrict__ ad, float* __restrict__ ws){
  const int tid = threadIdx.x;
  const int lane = tid & 63, w = tid >> 6;
  const int rowbase = blockIdx.x * 64;
  const int mrow = rowbase + w*16 + (lane & 15);
  const int koff = (lane >> 4) << 3;
  const short8v* WTB = (const short8v*)(ws + O_WTB);
  const short8v* WAB = (const short8v*)(ws + O_WAB);
  f32x4 accT0 = {0,0,0,0}, accT1 = {0,0,0,0};

  const f32x4* hp = (const f32x4*)(hs + (size_t)mrow*HH + koff);
  #pragma unroll 4
  for (int ks = 0; ks < 24; ++ks){
    f32x4 p0 = __builtin_nontemporal_load(hp + ks*8);
    f32x4 p1 = __builtin_nontemporal_load(hp + ks*8 + 1);
    short8v a = pack8(p0, p1);
    accT0 = __builtin_amdgcn_mfma_f32_16x16x32_bf16(a, WTB[ks*64 + lane], accT0, 0, 0, 0);
    accT1 = __builtin_amdgcn_mfma_f32_16x16x32_bf16(a, WTB[(24 + ks)*64 + lane], accT1, 0, 0, 0);
  }

  f32x4 accA0 = {0,0,0,0}, accA1 = {0,0,0,0};
  const f32x4* ap = (const f32x4*)(ad + (size_t)mrow*FDD + koff);
  #pragma unroll
  for (int ks = 0; ks < 2; ++ks){
    f32x4 q0 = __builtin_nontemporal_load(ap + ks*8);
    f32x4 q1 = __builtin_nontemporal_load(ap + ks*8 + 1);
    short8v a = pack8(q0, q1);
    accA0 = __builtin_amdgcn_mfma_f32_16x16x32_bf16(a, WAB[ks*64 + lane], accA0, 0, 0, 0);
    accA1 = __builtin_amdgcn_mfma_f32_16x16x32_bf16(a, WAB[(2 + ks)*64 + lane], accA1, 0, 0, 0);
  }

  // epilogue: C layout col(p)=lane&15, row=(lane>>4)*4+r
  float* TF = ws + O_TEXTF;   // [32][16384]
  float* AF = ws + O_AUDF;
  unsigned short* TEXTB = (unsigned short*)(ws + O_TEXTB);  // [16384][32]
  unsigned short* AUDB  = (unsigned short*)(ws + O_AUDB);
  const int q4 = lane >> 4, pl = lane & 15;
  const int row0 = rowbase + w*16 + q4*4;
  float sq = 0.0f;
  #pragma unroll
  for (int r = 0; r < 4; ++r) sq += accT0[r]*accT0[r] + accT1[r]*accT1[r];
  *(f32x4*)(TF + (size_t)pl*NR + row0)      = accT0;
  *(f32x4*)(TF + (size_t)(pl+16)*NR + row0) = accT1;
  *(f32x4*)(AF + (size_t)pl*NR + row0)      = accA0;
  *(f32x4*)(AF + (size_t)(pl+16)*NR + row0) = accA1;
  #pragma unroll
  for (int r = 0; r < 4; ++r){
    int row = row0 + r;
    TEXTB[(size_t)row*32 + pl]      = f2bf(accT0[r]);
    TEXTB[(size_t)row*32 + 16 + pl] = f2bf(accT1[r]);
    AUDB[(size_t)row*32 + pl]       = f2bf(accA0[r]);
    AUDB[(size_t)row*32 + 16 + pl]  = f2bf(accA1[r]);
  }
  #pragma unroll
  for (int off = 32; off; off >>= 1) sq += __shfl_xor(sq, off);
  if (lane == 0) atomicAdd(ws + O_SUMSQ, sq);
}

// ---- gram via bf16 MFMA, swapped operands -> f32x4 NT stores along t ----
__global__ __launch_bounds__(256) void k_gram(const float* __restrict__ ws,
    const float* __restrict__ twp, const float* __restrict__ awp, const float* __restrict__ fbp,
    float* __restrict__ out_text, float* __restrict__ out_fus){
  const int tid = threadIdx.x, lane = tid & 63, w = tid >> 6;
  const int tt = blockIdx.x, st = blockIdx.y, b = blockIdx.z;
  const unsigned short* TEXTB = (const unsigned short*)(ws + O_TEXTB);
  const unsigned short* AUDB  = (const unsigned short*)(ws + O_AUDB);
  const int q4 = lane >> 4, pl = lane & 15;
  const size_t srow  = (size_t)b*SS + st*64 + w*16 + pl;   // s-row for this lane
  const size_t trow0 = (size_t)b*SS + tt*64 + pl;          // t-row base
  short8v at = *(const short8v*)&TEXTB[srow*32 + q4*8];    // B-operand (s)
  short8v aa = *(const short8v*)&AUDB [srow*32 + q4*8];
  f32x4 z = {0,0,0,0};
  f32x4 ct[4], ca[4];
  #pragma unroll
  for (int n = 0; n < 4; ++n){
    short8v bt = *(const short8v*)&TEXTB[(trow0 + n*16)*32 + q4*8];  // A-operand (t)
    short8v ba = *(const short8v*)&AUDB [(trow0 + n*16)*32 + q4*8];
    ct[n] = __builtin_amdgcn_mfma_f32_16x16x32_bf16(bt, at, z, 0, 0, 0);  // D[t][s]
    ca[n] = __builtin_amdgcn_mfma_f32_16x16x32_bf16(ba, aa, z, 0, 0, 0);
  }
  const float inv_s = 1.0f / sqrtf(ws[O_SUMSQ]);
  const float tw = twp[0], aw = awp[0], fb = fbp[0];
  const int s = st*64 + w*16 + pl;          // output row (col of D)
  const int tbase = tt*64;                  // D rows are t
  #pragma unroll
  for (int n = 0; n < 4; ++n){
    f32x4 vt, vf;
    #pragma unroll
    for (int r = 0; r < 4; ++r){
      float t_ = fmaxf(ct[n][r]*inv_s, 0.0f);
      float a_ = fmaxf(ca[n][r], 0.0f);
      vt[r] = t_;
      vf[r] = fmaxf(tw*t_ + aw*a_ + fb, 0.0f);
    }
    size_t o = ((size_t)b*SS + s)*SS + tbase + n*16 + q4*4;
    __builtin_nontemporal_store(vt, (f32x4*)(out_text + o));
    __builtin_nontemporal_store(vf, (f32x4*)(out_fus  + o));
  }
}

// ---- row-0 scores + softmax fused: one block of 512 per batch ----
__global__ __launch_bounds__(512) void k_att(float* __restrict__ ws, const float* __restrict__ amask,
    const float* __restrict__ twp, const float* __restrict__ awp, const float* __restrict__ fbp){
  const int b = blockIdx.x, tid = threadIdx.x;
  __shared__ float t0[32], a0[32];
  __shared__ float red[512];
  const float* TF = ws + O_TEXTF;
  const float* AF = ws + O_AUDF;
  if (tid < 32) t0[tid] = TF[(size_t)tid*NR + (size_t)b*SS];
  else if (tid < 64) a0[tid-32] = AF[(size_t)(tid-32)*NR + (size_t)b*SS];
  __syncthreads();
  const float inv_s = 1.0f / sqrtf(ws[O_SUMSQ]);
  const float tw = twp[0], aw = awp[0], fb = fbp[0];
  const float m0 = amask[(size_t)b*SS];
  const size_t base = (size_t)b*SS + tid;
  float dt = 0.f, da = 0.f;
  #pragma unroll
  for (int p = 0; p < 32; ++p){
    dt += t0[p]*TF[(size_t)p*NR + base];
    da += a0[p]*AF[(size_t)p*NR + base];
  }
  const float sv = tw*fmaxf(dt*inv_s, 0.f) + aw*fmaxf(da, 0.f) + fb
                 + amask[base] + m0;
  red[tid] = sv;
  __syncthreads();
  for (int s2 = 256; s2 > 0; s2 >>= 1){ if (tid < s2) red[tid] = fmaxf(red[tid], red[tid+s2]); __syncthreads(); }
  const float m = red[0];
  __syncthreads();
  const float e = __expf(sv - m);
  red[tid] = e;
  __syncthreads();
  for (int s2 = 256; s2 > 0; s2 >>= 1){ if (tid < s2) red[tid] += red[tid+s2]; __syncthreads(); }
  ws[O_ATT + base] = e / red[0];
}

// ---- row-0 PV: (3 c-chunks, 8 t-chunks, 32 b); NT loads on single-use hs ----
__global__ __launch_bounds__(256) void k_pv(const float* __restrict__ hs, float* __restrict__ ws){
  const int tid = threadIdx.x;
  const int cx = blockIdx.x, th = blockIdx.y, b = blockIdx.z;
  __shared__ float a[64];
  if (tid < 64) a[tid] = ws[O_ATT + (size_t)b*SS + th*64 + tid];
  __syncthreads();
  const int c = cx*256 + tid;
  const float* hp = hs + ((size_t)b*SS + th*64)*HH + c;
  float acc = 0.f;
  #pragma unroll 8
  for (int t = 0; t < 64; ++t) acc += a[t]*__builtin_nontemporal_load(hp + (size_t)t*HH);
  if (th == 0) acc += hs[(size_t)b*SS*HH + c];   // residual
  ws[O_FPART + ((size_t)th*BB + b)*HH + c] = acc;
}

// ---- dense split-K: block (kc, b) handles 64 c-values, all 768 outputs ----
__global__ __launch_bounds__(256) void k_dense(float* __restrict__ ws){
  const int kc = blockIdx.x, b = blockIdx.y, tid = threadIdx.x;
  __shared__ float fc[64];
  if (tid < 64){
    float s = 0.f;
    const int c = kc*64 + tid;
    #pragma unroll
    for (int th = 0; th < 8; ++th) s += ws[O_FPART + ((size_t)th*BB + b)*HH + c];
    fc[tid] = s;
  }
  __syncthreads();
  const float* Wp = ws + O_WDT + (size_t)(kc*64)*HH;
  float a0 = 0.f, a1 = 0.f, a2 = 0.f;
  #pragma unroll 8
  for (int i = 0; i < 64; ++i){
    const float fv = fc[i];
    const float* wr = Wp + (size_t)i*HH + tid;
    a0 += fv*wr[0];
    a1 += fv*wr[256];
    a2 += fv*wr[512];
  }
  float* hp = ws + O_HPART + ((size_t)kc*BB + b)*HH;
  hp[tid]       = a0;
  hp[tid + 256] = a1;
  hp[tid + 512] = a2;
}

// ---- LN over 12 dense partials ----
__global__ __launch_bounds__(256) void k_ln(const float* __restrict__ ws,
    const float* __restrict__ bd, const float* __restrict__ lw, const float* __restrict__ lb,
    float* __restrict__ out){
  const int b = blockIdx.x, tid = threadIdx.x;
  __shared__ float red[256];
  float a0 = bd[tid], a1 = bd[tid+256], a2 = bd[tid+512];
  #pragma unroll
  for (int kc = 0; kc < 12; ++kc){
    const float* hp = ws + O_HPART + ((size_t)kc*BB + b)*HH;
    a0 += hp[tid];
    a1 += hp[tid + 256];
    a2 += hp[tid + 512];
  }
  red[tid] = a0 + a1 + a2;
  __syncthreads();
  for (int s2 = 128; s2 > 0; s2 >>= 1){ if (tid < s2) red[tid] += red[tid+s2]; __syncthreads(); }
  const float u = red[0]*(1.0f/HH);
  __syncthreads();
  const float d0 = a0-u, d1 = a1-u, d2 = a2-u;
  red[tid] = d0*d0 + d1*d1 + d2*d2;
  __syncthreads();
  for (int s2 = 128; s2 > 0; s2 >>= 1){ if (tid < s2) red[tid] += red[tid+s2]; __syncthreads(); }
  const float isd = 1.0f / sqrtf(red[0]*(1.0f/HH) + 1e-12f);
  out[(size_t)b*HH + tid]     = lw[tid]    *d0*isd + lb[tid];
  out[(size_t)b*HH + tid+256] = lw[tid+256]*d1*isd + lb[tid+256];
  out[(size_t)b*HH + tid+512] = lw[tid+512]*d2*isd + lb[tid+512];
}

extern "C" void kernel_launch(void* const* d_in, const int* in_sizes, int n_in,
                              void* d_out, int out_size, void* d_ws, size_t ws_size,
                              hipStream_t stream){
  const float* hs    = (const float*)d_in[0];
  const float* ad    = (const float*)d_in[1];
  const float* amask = (const float*)d_in[2];
  const float* Wt    = (const float*)d_in[3];
  const float* Wa    = (const float*)d_in[4];
  const float* twp   = (const float*)d_in[5];
  const float* awp   = (const float*)d_in[6];
  const float* fbp   = (const float*)d_in[7];
  const float* Wd    = (const float*)d_in[8];
  const float* bd    = (const float*)d_in[9];
  const float* lw    = (const float*)d_in[10];
  const float* lb    = (const float*)d_in[11];
  float* out = (float*)d_out;
  float* ws  = (float*)d_ws;
  float* out_h    = out;
  float* out_text = out + (size_t)BB*HH;
  float* out_fus  = out_text + (size_t)BB*SS*SS;

  hipLaunchKernelGGL(k_prep, dim3(681), dim3(256), 0, stream, Wd, Wt, Wa, ws);
  hipLaunchKernelGGL(k_proj, dim3(NR/64), dim3(256), 0, stream, hs, ad, ws);
  hipLaunchKernelGGL(k_gram, dim3(8,8,BB), dim3(256), 0, stream, ws, twp, awp, fbp, out_text, out_fus);
  hipLaunchKernelGGL(k_att, dim3(BB), dim3(512), 0, stream, ws, amask, twp, awp, fbp);
  hipLaunchKernelGGL(k_pv, dim3(3,8,BB), dim3(256), 0, stream, hs, ws);
  hipLaunchKernelGGL(k_dense, dim3(12,BB), dim3(256), 0, stream, ws);
  hipLaunchKernelGGL(k_ln, dim3(BB), dim3(256), 0, stream, ws, bd, lw, lb, out_h);
}

// Round 11
// 175.435 us; speedup vs baseline: 1.0648x; 1.0392x over previous
//
#include <hip/hip_runtime.h>
#include <math.h>

#define BB 32
#define SS 512
#define HH 768
#define FDD 64
#define PP 30
#define NR 16384   // BB*SS rows

typedef __attribute__((ext_vector_type(8))) short short8v;
typedef __attribute__((ext_vector_type(4))) float f32x4;

// ws float offsets
#define O_TEXTF  0u        // fp32 text TRANSPOSED [32][16384]
#define O_AUDF   524288u   // fp32 audio TRANSPOSED [32][16384]
#define O_ATT    1048576u  // 32*512 att weights
#define O_FPART  1081344u  // 8*32*768 pv partials
#define O_HPART  1277952u  // 12*32*768 dense partials
#define O_WDT    1572864u  // 768*768 transposed W_dense
#define O_WTB    2162688u  // 24576 ushort (bf16 Wt frag-ordered)
#define O_WAB    2174976u  // 2048 ushort  (bf16 Wa frag-ordered)
#define O_TEXTB  2176000u  // bf16 text  [16384][32]
#define O_AUDB   2438144u  // bf16 audio [16384][32]
#define O_SUMSQ  2700288u  // 1

__device__ __forceinline__ unsigned short f2bf(float f){
  unsigned u = __float_as_uint(f);
  unsigned r = (u + 0x7fffu + ((u>>16)&1u)) >> 16;   // RNE
  return (unsigned short)r;
}
__device__ __forceinline__ short8v pack8(const f32x4& p0, const f32x4& p1){
  union { short8v v; unsigned u[4]; } r;
  r.u[0] = f2bf(p0[0]) | ((unsigned)f2bf(p0[1]) << 16);
  r.u[1] = f2bf(p0[2]) | ((unsigned)f2bf(p0[3]) << 16);
  r.u[2] = f2bf(p1[0]) | ((unsigned)f2bf(p1[1]) << 16);
  r.u[3] = f2bf(p1[2]) | ((unsigned)f2bf(p1[3]) << 16);
  return r.v;
}

// ---- prep: LDS-tiled WdT transpose (0..575), bf16 frag Wt/Wa (576..679), sumsq zero (680) ----
__global__ __launch_bounds__(256) void k_prep(const float* __restrict__ Wd,
    const float* __restrict__ Wt, const float* __restrict__ Wa, float* __restrict__ ws){
  const int bi = blockIdx.x, tid = threadIdx.x;
  if (bi < 576){
    __shared__ float L[32][33];
    const int tx = bi % 24, ty = bi / 24;
    const int lx = tid & 31, ly = tid >> 5;
    #pragma unroll
    for (int i = 0; i < 4; ++i)
      L[ly + i*8][lx] = Wd[(size_t)(ty*32 + ly + i*8)*HH + tx*32 + lx];
    __syncthreads();
    #pragma unroll
    for (int i = 0; i < 4; ++i)
      ws[O_WDT + (size_t)(tx*32 + ly + i*8)*HH + ty*32 + lx] = L[lx][ly + i*8];
  } else if (bi < 680){
    int idx = (bi - 576)*256 + tid;
    if (idx < 24576){
      int j = idx & 7, lane = (idx>>3) & 63, t = idx>>9;   // t = n*24+ks
      int n = t / 24, ks = t - n*24;
      int p = n*16 + (lane & 15);
      int k = ks*32 + ((lane>>4)<<3) + j;
      float v = (p < PP) ? Wt[p*HH + k] : 0.0f;
      ((unsigned short*)(ws + O_WTB))[idx] = f2bf(v);
    } else {
      int fa = idx - 24576;   // < 2048
      int j = fa & 7, lane = (fa>>3) & 63, t = fa>>9;      // t = n*2+ks
      int n = t>>1, ks = t & 1;
      int p = n*16 + (lane & 15);
      int k = ks*32 + ((lane>>4)<<3) + j;
      float v = (p < PP) ? Wa[p*FDD + k] : 0.0f;
      ((unsigned short*)(ws + O_WAB))[fa] = f2bf(v);
    }
  } else if (tid == 0){
    ws[O_SUMSQ] = 0.0f;
  }
}

// ---- projection via bf16 MFMA, no LDS/barriers; cached loads (hs is L3-resident, re-read by pv) ----
__global__ __launch_bounds__(256) void k_proj(const float* __restrict__ hs,
    const float* __restrict__ ad, float* __restrict__ ws){
  const int tid = threadIdx.x;
  const int lane = tid & 63, w = tid >> 6;
  const int rowbase = blockIdx.x * 64;
  const int mrow = rowbase + w*16 + (lane & 15);
  const int koff = (lane >> 4) << 3;
  const short8v* WTB = (const short8v*)(ws + O_WTB);
  const short8v* WAB = (const short8v*)(ws + O_WAB);
  f32x4 accT0 = {0,0,0,0}, accT1 = {0,0,0,0};

  const f32x4* hp = (const f32x4*)(hs + (size_t)mrow*HH + koff);
  #pragma unroll 4
  for (int ks = 0; ks < 24; ++ks){
    f32x4 p0 = hp[ks*8];
    f32x4 p1 = hp[ks*8 + 1];
    short8v a = pack8(p0, p1);
    accT0 = __builtin_amdgcn_mfma_f32_16x16x32_bf16(a, WTB[ks*64 + lane], accT0, 0, 0, 0);
    accT1 = __builtin_amdgcn_mfma_f32_16x16x32_bf16(a, WTB[(24 + ks)*64 + lane], accT1, 0, 0, 0);
  }

  f32x4 accA0 = {0,0,0,0}, accA1 = {0,0,0,0};
  const f32x4* ap = (const f32x4*)(ad + (size_t)mrow*FDD + koff);
  #pragma unroll
  for (int ks = 0; ks < 2; ++ks){
    f32x4 q0 = ap[ks*8];
    f32x4 q1 = ap[ks*8 + 1];
    short8v a = pack8(q0, q1);
    accA0 = __builtin_amdgcn_mfma_f32_16x16x32_bf16(a, WAB[ks*64 + lane], accA0, 0, 0, 0);
    accA1 = __builtin_amdgcn_mfma_f32_16x16x32_bf16(a, WAB[(2 + ks)*64 + lane], accA1, 0, 0, 0);
  }

  // epilogue: C layout col(p)=lane&15, row=(lane>>4)*4+r
  float* TF = ws + O_TEXTF;   // [32][16384]
  float* AF = ws + O_AUDF;
  unsigned short* TEXTB = (unsigned short*)(ws + O_TEXTB);  // [16384][32]
  unsigned short* AUDB  = (unsigned short*)(ws + O_AUDB);
  const int q4 = lane >> 4, pl = lane & 15;
  const int row0 = rowbase + w*16 + q4*4;
  float sq = 0.0f;
  #pragma unroll
  for (int r = 0; r < 4; ++r) sq += accT0[r]*accT0[r] + accT1[r]*accT1[r];
  *(f32x4*)(TF + (size_t)pl*NR + row0)      = accT0;
  *(f32x4*)(TF + (size_t)(pl+16)*NR + row0) = accT1;
  *(f32x4*)(AF + (size_t)pl*NR + row0)      = accA0;
  *(f32x4*)(AF + (size_t)(pl+16)*NR + row0) = accA1;
  #pragma unroll
  for (int r = 0; r < 4; ++r){
    int row = row0 + r;
    TEXTB[(size_t)row*32 + pl]      = f2bf(accT0[r]);
    TEXTB[(size_t)row*32 + 16 + pl] = f2bf(accT1[r]);
    AUDB[(size_t)row*32 + pl]       = f2bf(accA0[r]);
    AUDB[(size_t)row*32 + 16 + pl]  = f2bf(accA1[r]);
  }
  #pragma unroll
  for (int off = 32; off; off >>= 1) sq += __shfl_xor(sq, off);
  if (lane == 0) atomicAdd(ws + O_SUMSQ, sq);
}

// ---- gram via bf16 MFMA, swapped operands -> f32x4 NT stores along t ----
__global__ __launch_bounds__(256) void k_gram(const float* __restrict__ ws,
    const float* __restrict__ twp, const float* __restrict__ awp, const float* __restrict__ fbp,
    float* __restrict__ out_text, float* __restrict__ out_fus){
  const int tid = threadIdx.x, lane = tid & 63, w = tid >> 6;
  const int tt = blockIdx.x, st = blockIdx.y, b = blockIdx.z;
  const unsigned short* TEXTB = (const unsigned short*)(ws + O_TEXTB);
  const unsigned short* AUDB  = (const unsigned short*)(ws + O_AUDB);
  const int q4 = lane >> 4, pl = lane & 15;
  const size_t srow  = (size_t)b*SS + st*64 + w*16 + pl;   // s-row for this lane
  const size_t trow0 = (size_t)b*SS + tt*64 + pl;          // t-row base
  short8v at = *(const short8v*)&TEXTB[srow*32 + q4*8];    // B-operand (s)
  short8v aa = *(const short8v*)&AUDB [srow*32 + q4*8];
  f32x4 z = {0,0,0,0};
  f32x4 ct[4], ca[4];
  #pragma unroll
  for (int n = 0; n < 4; ++n){
    short8v bt = *(const short8v*)&TEXTB[(trow0 + n*16)*32 + q4*8];  // A-operand (t)
    short8v ba = *(const short8v*)&AUDB [(trow0 + n*16)*32 + q4*8];
    ct[n] = __builtin_amdgcn_mfma_f32_16x16x32_bf16(bt, at, z, 0, 0, 0);  // D[t][s]
    ca[n] = __builtin_amdgcn_mfma_f32_16x16x32_bf16(ba, aa, z, 0, 0, 0);
  }
  const float inv_s = 1.0f / sqrtf(ws[O_SUMSQ]);
  const float tw = twp[0], aw = awp[0], fb = fbp[0];
  const int s = st*64 + w*16 + pl;          // output row (col of D)
  const int tbase = tt*64;                  // D rows are t
  #pragma unroll
  for (int n = 0; n < 4; ++n){
    f32x4 vt, vf;
    #pragma unroll
    for (int r = 0; r < 4; ++r){
      float t_ = fmaxf(ct[n][r]*inv_s, 0.0f);
      float a_ = fmaxf(ca[n][r], 0.0f);
      vt[r] = t_;
      vf[r] = fmaxf(tw*t_ + aw*a_ + fb, 0.0f);
    }
    size_t o = ((size_t)b*SS + s)*SS + tbase + n*16 + q4*4;
    __builtin_nontemporal_store(vt, (f32x4*)(out_text + o));
    __builtin_nontemporal_store(vf, (f32x4*)(out_fus  + o));
  }
}

// ---- row-0 scores + softmax fused: one block of 512 per batch ----
__global__ __launch_bounds__(512) void k_att(float* __restrict__ ws, const float* __restrict__ amask,
    const float* __restrict__ twp, const float* __restrict__ awp, const float* __restrict__ fbp){
  const int b = blockIdx.x, tid = threadIdx.x;
  __shared__ float t0[32], a0[32];
  __shared__ float red[512];
  const float* TF = ws + O_TEXTF;
  const float* AF = ws + O_AUDF;
  if (tid < 32) t0[tid] = TF[(size_t)tid*NR + (size_t)b*SS];
  else if (tid < 64) a0[tid-32] = AF[(size_t)(tid-32)*NR + (size_t)b*SS];
  __syncthreads();
  const float inv_s = 1.0f / sqrtf(ws[O_SUMSQ]);
  const float tw = twp[0], aw = awp[0], fb = fbp[0];
  const float m0 = amask[(size_t)b*SS];
  const size_t base = (size_t)b*SS + tid;
  float dt = 0.f, da = 0.f;
  #pragma unroll
  for (int p = 0; p < 32; ++p){
    dt += t0[p]*TF[(size_t)p*NR + base];
    da += a0[p]*AF[(size_t)p*NR + base];
  }
  const float sv = tw*fmaxf(dt*inv_s, 0.f) + aw*fmaxf(da, 0.f) + fb
                 + amask[base] + m0;
  red[tid] = sv;
  __syncthreads();
  for (int s2 = 256; s2 > 0; s2 >>= 1){ if (tid < s2) red[tid] = fmaxf(red[tid], red[tid+s2]); __syncthreads(); }
  const float m = red[0];
  __syncthreads();
  const float e = __expf(sv - m);
  red[tid] = e;
  __syncthreads();
  for (int s2 = 256; s2 > 0; s2 >>= 1){ if (tid < s2) red[tid] += red[tid+s2]; __syncthreads(); }
  ws[O_ATT + base] = e / red[0];
}

// ---- row-0 PV: (3 c-chunks, 8 t-chunks, 32 b); cached loads (hs from L3 after proj) ----
__global__ __launch_bounds__(256) void k_pv(const float* __restrict__ hs, float* __restrict__ ws){
  const int tid = threadIdx.x;
  const int cx = blockIdx.x, th = blockIdx.y, b = blockIdx.z;
  __shared__ float a[64];
  if (tid < 64) a[tid] = ws[O_ATT + (size_t)b*SS + th*64 + tid];
  __syncthreads();
  const int c = cx*256 + tid;
  const float* hp = hs + ((size_t)b*SS + th*64)*HH + c;
  float acc = 0.f;
  #pragma unroll 8
  for (int t = 0; t < 64; ++t) acc += a[t]*hp[(size_t)t*HH];
  if (th == 0) acc += hs[(size_t)b*SS*HH + c];   // residual
  ws[O_FPART + ((size_t)th*BB + b)*HH + c] = acc;
}

// ---- dense split-K: block (kc, b) handles 64 c-values, all 768 outputs ----
__global__ __launch_bounds__(256) void k_dense(float* __restrict__ ws){
  const int kc = blockIdx.x, b = blockIdx.y, tid = threadIdx.x;
  __shared__ float fc[64];
  if (tid < 64){
    float s = 0.f;
    const int c = kc*64 + tid;
    #pragma unroll
    for (int th = 0; th < 8; ++th) s += ws[O_FPART + ((size_t)th*BB + b)*HH + c];
    fc[tid] = s;
  }
  __syncthreads();
  const float* Wp = ws + O_WDT + (size_t)(kc*64)*HH;
  float a0 = 0.f, a1 = 0.f, a2 = 0.f;
  #pragma unroll 8
  for (int i = 0; i < 64; ++i){
    const float fv = fc[i];
    const float* wr = Wp + (size_t)i*HH + tid;
    a0 += fv*wr[0];
    a1 += fv*wr[256];
    a2 += fv*wr[512];
  }
  float* hp = ws + O_HPART + ((size_t)kc*BB + b)*HH;
  hp[tid]       = a0;
  hp[tid + 256] = a1;
  hp[tid + 512] = a2;
}

// ---- LN over 12 dense partials ----
__global__ __launch_bounds__(256) void k_ln(const float* __restrict__ ws,
    const float* __restrict__ bd, const float* __restrict__ lw, const float* __restrict__ lb,
    float* __restrict__ out){
  const int b = blockIdx.x, tid = threadIdx.x;
  __shared__ float red[256];
  float a0 = bd[tid], a1 = bd[tid+256], a2 = bd[tid+512];
  #pragma unroll
  for (int kc = 0; kc < 12; ++kc){
    const float* hp = ws + O_HPART + ((size_t)kc*BB + b)*HH;
    a0 += hp[tid];
    a1 += hp[tid + 256];
    a2 += hp[tid + 512];
  }
  red[tid] = a0 + a1 + a2;
  __syncthreads();
  for (int s2 = 128; s2 > 0; s2 >>= 1){ if (tid < s2) red[tid] += red[tid+s2]; __syncthreads(); }
  const float u = red[0]*(1.0f/HH);
  __syncthreads();
  const float d0 = a0-u, d1 = a1-u, d2 = a2-u;
  red[tid] = d0*d0 + d1*d1 + d2*d2;
  __syncthreads();
  for (int s2 = 128; s2 > 0; s2 >>= 1){ if (tid < s2) red[tid] += red[tid+s2]; __syncthreads(); }
  const float isd = 1.0f / sqrtf(red[0]*(1.0f/HH) + 1e-12f);
  out[(size_t)b*HH + tid]     = lw[tid]    *d0*isd + lb[tid];
  out[(size_t)b*HH + tid+256] = lw[tid+256]*d1*isd + lb[tid+256];
  out[(size_t)b*HH + tid+512] = lw[tid+512]*d2*isd + lb[tid+512];
}

extern "C" void kernel_launch(void* const* d_in, const int* in_sizes, int n_in,
                              void* d_out, int out_size, void* d_ws, size_t ws_size,
                              hipStream_t stream){
  const float* hs    = (const float*)d_in[0];
  const float* ad    = (const float*)d_in[1];
  const float* amask = (const float*)d_in[2];
  const float* Wt    = (const float*)d_in[3];
  const float* Wa    = (const float*)d_in[4];
  const float* twp   = (const float*)d_in[5];
  const float* awp   = (const float*)d_in[6];
  const float* fbp   = (const float*)d_in[7];
  const float* Wd    = (const float*)d_in[8];
  const float* bd    = (const float*)d_in[9];
  const float* lw    = (const float*)d_in[10];
  const float* lb    = (const float*)d_in[11];
  float* out = (float*)d_out;
  float* ws  = (float*)d_ws;
  float* out_h    = out;
  float* out_text = out + (size_t)BB*HH;
  float* out_fus  = out_text + (size_t)BB*SS*SS;

  hipLaunchKernelGGL(k_prep, dim3(681), dim3(256), 0, stream, Wd, Wt, Wa, ws);
  hipLaunchKernelGGL(k_proj, dim3(NR/64), dim3(256), 0, stream, hs, ad, ws);
  hipLaunchKernelGGL(k_gram, dim3(8,8,BB), dim3(256), 0, stream, ws, twp, awp, fbp, out_text, out_fus);
  hipLaunchKernelGGL(k_att, dim3(BB), dim3(512), 0, stream, ws, amask, twp, awp, fbp);
  hipLaunchKernelGGL(k_pv, dim3(3,8,BB), dim3(256), 0, stream, hs, ws);
  hipLaunchKernelGGL(k_dense, dim3(12,BB), dim3(256), 0, stream, ws);
  hipLaunchKernelGGL(k_ln, dim3(BB), dim3(256), 0, stream, ws, bd, lw, lb, out_h);
}